// Round 6
// baseline (203.318 us; speedup 1.0000x reference)
//
#include <hip/hip_runtime.h>

// CP-rank-32 tensor reconstruction: out[i,j,k] = sum_r W0[i,r]*W1[j,r]*W2[k,r]
// out 256x256x1024 fp32 (268 MB). Fill kernel proves 6.9 TB/s plain-store write.
// Evidence: R3(NT,LDS-c)=80us, R4(NT,reg-w)=80us -> NT write path caps ~3.35 TB/s.
//           R5(plain,reads-in-loop)=118us -> plain stores + L2 reads interfere.
// R6: plain stores + ZERO global reads in hot loop (c in LDS, w in regs).
// FMA order per output element: r=0..31 sequential fused — bit-exact (absmax 0.0).

constexpr int I_DIM = 256;
constexpr int J_DIM = 256;
constexpr int K_DIM = 1024;
constexpr int RNK   = 32;
constexpr int JSEG  = 64;   // j's per block

// W2 (1024x32, row-major) -> W2T (32x1024): register loads coalesced in k.
__global__ void transpose_w2(const float* __restrict__ W2, float* __restrict__ W2T) {
    int idx = blockIdx.x * 256 + threadIdx.x;   // 0 .. 32767
    int r = idx >> 10;
    int k = idx & (K_DIM - 1);
    W2T[r * K_DIM + k] = W2[k * RNK + r];
}

// Block: one i, JSEG j's, all k (thread = one k-float4).
// Hot loop: LDS broadcast + FMA + plain store. No global reads.
__global__ __launch_bounds__(256, 2) void cp_recon_h(const float* __restrict__ W0,
                                                     const float* __restrict__ W1,
                                                     const float* __restrict__ W2T,
                                                     float* __restrict__ out) {
    __shared__ __align__(16) float c[JSEG][RNK];   // 8 KB
    const int i     = blockIdx.x >> 2;             // / (J_DIM/JSEG)
    const int jbase = (blockIdx.x & 3) * JSEG;
    const int tid   = threadIdx.x;

    // c[jj][r] = W0[i,r] * W1[jbase+jj, r]  — cooperative, 2048 entries.
#pragma unroll
    for (int t = 0; t < (JSEG * RNK) / 256; ++t) {
        int idx = tid + t * 256;
        int jj = idx >> 5;
        int r  = idx & 31;
        c[jj][r] = W0[i * RNK + r] * W1[(jbase + jj) * RNK + r];
    }

    // Whole rank-32 W2T slice for this thread's 4 k's: 32 float4 = 128 VGPRs.
    const int k = tid * 4;
    float4 w[RNK];
#pragma unroll
    for (int r = 0; r < RNK; ++r)
        w[r] = *reinterpret_cast<const float4*>(&W2T[r * K_DIM + k]);

    __syncthreads();

    float* __restrict__ orow = out + (size_t)(i * J_DIM + jbase) * K_DIM + k;

#pragma unroll 1
    for (int jj = 0; jj < JSEG; ++jj) {
        float4 acc = make_float4(0.f, 0.f, 0.f, 0.f);
#pragma unroll
        for (int r = 0; r < RNK; ++r) {
            float s = c[jj][r];                    // same addr all lanes: broadcast
            acc.x = fmaf(s, w[r].x, acc.x);
            acc.y = fmaf(s, w[r].y, acc.y);
            acc.z = fmaf(s, w[r].z, acc.z);
            acc.w = fmaf(s, w[r].w, acc.w);
        }
        *reinterpret_cast<float4*>(orow + (size_t)jj * K_DIM) = acc;  // plain store
    }
}

// ---- Fallback (no ws): direct W2 reads, LDS-c, JT=8 (R3 structure) ----
constexpr int JT = 8;
__global__ __launch_bounds__(256, 4) void cp_recon_d(const float* __restrict__ W0,
                                                     const float* __restrict__ W1,
                                                     const float* __restrict__ W2,
                                                     float* __restrict__ out) {
    __shared__ __align__(16) float c[JT][RNK];
    const int i     = blockIdx.x >> 5;
    const int jbase = (blockIdx.x & 31) * JT;
    const int tid   = threadIdx.x;

    if (tid < JT * RNK) {
        int jj = tid >> 5;
        int r  = tid & 31;
        c[jj][r] = W0[i * RNK + r] * W1[(jbase + jj) * RNK + r];
    }
    __syncthreads();

    const int k = tid * 4;
    float4 acc[JT];
#pragma unroll
    for (int jj = 0; jj < JT; ++jj) acc[jj] = make_float4(0.f, 0.f, 0.f, 0.f);

    for (int rc = 0; rc < RNK; rc += 4) {
        float4 row[4];
#pragma unroll
        for (int q = 0; q < 4; ++q)
            row[q] = *reinterpret_cast<const float4*>(&W2[(k + q) * RNK + rc]);
#pragma unroll
        for (int jj = 0; jj < JT; ++jj) {
            float4 c4 = *reinterpret_cast<const float4*>(&c[jj][rc]);
            acc[jj].x = fmaf(c4.x, row[0].x, fmaf(c4.y, row[0].y, fmaf(c4.z, row[0].z, fmaf(c4.w, row[0].w, acc[jj].x))));
            acc[jj].y = fmaf(c4.x, row[1].x, fmaf(c4.y, row[1].y, fmaf(c4.z, row[1].z, fmaf(c4.w, row[1].w, acc[jj].y))));
            acc[jj].z = fmaf(c4.x, row[2].x, fmaf(c4.y, row[2].y, fmaf(c4.z, row[2].z, fmaf(c4.w, row[2].w, acc[jj].z))));
            acc[jj].w = fmaf(c4.x, row[3].x, fmaf(c4.y, row[3].y, fmaf(c4.z, row[3].z, fmaf(c4.w, row[3].w, acc[jj].w))));
        }
    }
#pragma unroll
    for (int jj = 0; jj < JT; ++jj) {
        int o = (i * J_DIM + jbase + jj) * K_DIM + k;
        *reinterpret_cast<float4*>(&out[o]) = acc[jj];
    }
}

extern "C" void kernel_launch(void* const* d_in, const int* in_sizes, int n_in,
                              void* d_out, int out_size, void* d_ws, size_t ws_size,
                              hipStream_t stream) {
    const float* W0 = (const float*)d_in[0];
    const float* W1 = (const float*)d_in[1];
    const float* W2 = (const float*)d_in[2];
    float* out = (float*)d_out;

    const size_t w2t_bytes = (size_t)RNK * K_DIM * sizeof(float);  // 128 KB

    if (ws_size >= w2t_bytes) {
        float* W2T = (float*)d_ws;
        transpose_w2<<<(RNK * K_DIM) / 256, 256, 0, stream>>>(W2, W2T);
        cp_recon_h<<<I_DIM * (J_DIM / JSEG), 256, 0, stream>>>(W0, W1, W2T, out);
    } else {
        cp_recon_d<<<I_DIM * (J_DIM / JT), 256, 0, stream>>>(W0, W1, W2, out);
    }
}

// Round 7
// 78.437 us; speedup vs baseline: 2.5921x; 2.5921x over previous
//
#include <hip/hip_runtime.h>

// CP-rank-32: out[i,j,k] = sum_r W0[i,r]*W1[j,r]*W2[k,r]; out 256x256x1024 fp32 (268MB).
// Model after R3-R6: all variants stall-bound at 2 waves/SIMD (R6: 0 global reads in
// loop, plain stores, still 218us, VALUBusy 19%). Fill kernel (8 VGPR, many waves,
// plain stores) = 6.9 TB/s -> latency hiding is everything.
// R7: float2/thread -> w[32] = 64 VGPR (total ~80 -> ~6 waves/SIMD), c via SMEM
// (wave-uniform loads of precomputed C, 0 VGPR), NT stores (keep L2 clean for c).
// Discriminator: ~50-60us => stall theory; ~80us => real NT write cap (R8: plain+SGPR-c).
// FMA order r=0..31 sequential per element — bit-exact across all rounds (absmax 0.0).

constexpr int I_DIM  = 256;
constexpr int J_DIM  = 256;
constexpr int K_DIM  = 1024;
constexpr int RNK    = 32;
constexpr int JSEG   = 64;            // j's per block
constexpr int KSPLIT = 2;             // k-halves
constexpr int KCHUNK = K_DIM / KSPLIT; // 512 k's per block (256 thr * float2)

typedef float f32x2 __attribute__((ext_vector_type(2)));

// W2 (1024x32) -> W2T (32x1024): w loads coalesced in k.
__global__ void transpose_w2(const float* __restrict__ W2, float* __restrict__ W2T) {
    int idx = blockIdx.x * 256 + threadIdx.x;   // 0 .. 32767
    int r = idx >> 10;
    int k = idx & (K_DIM - 1);
    W2T[r * K_DIM + k] = W2[k * RNK + r];
}

// C[i][j][r] = W0[i,r] * W1[j,r]   (8 MB)
__global__ void precompute_c(const float* __restrict__ W0, const float* __restrict__ W1,
                             float* __restrict__ C) {
    int idx = blockIdx.x * 256 + threadIdx.x;
    int r = idx & 31;
    int j = (idx >> 5) & 255;
    int i = idx >> 13;
    C[idx] = W0[i * RNK + r] * W1[j * RNK + r];
}

// Block: (i, jseg, khalf). Thread: one k-float2. w[32] float2 in regs, c via SMEM.
__global__ __launch_bounds__(256, 4) void cp_recon_f2(const float* __restrict__ C,
                                                      const float* __restrict__ W2T,
                                                      float* __restrict__ out) {
    const int b     = blockIdx.x;
    const int khalf = b & (KSPLIT - 1);
    const int jseg  = (b >> 1) & 3;             // J_DIM/JSEG = 4
    const int i     = b >> 3;
    const int jbase = jseg * JSEG;
    const int k     = khalf * KCHUNK + threadIdx.x * 2;

    // Rank-32 W2T slice for this thread's 2 k's: 32 float2 = 64 VGPRs, loaded once.
    float2 w[RNK];
#pragma unroll
    for (int r = 0; r < RNK; ++r)
        w[r] = *reinterpret_cast<const float2*>(&W2T[r * K_DIM + k]);

    const float* __restrict__ crow = C + (size_t)(i * J_DIM + jbase) * RNK;
    float* __restrict__ obase = out + (size_t)(i * J_DIM + jbase) * K_DIM + k;

#pragma unroll 2
    for (int jj = 0; jj < JSEG; ++jj) {
        const float* __restrict__ cj = crow + jj * RNK;  // wave-uniform -> s_load
        float ax = 0.f, ay = 0.f;
#pragma unroll
        for (int r = 0; r < RNK; ++r) {
            float s = cj[r];
            ax = fmaf(s, w[r].x, ax);
            ay = fmaf(s, w[r].y, ay);
        }
        f32x2 t = { ax, ay };
        __builtin_nontemporal_store(t, reinterpret_cast<f32x2*>(obase + (size_t)jj * K_DIM));
    }
}

// ---- Fallback (no ws): direct W2 reads, LDS-c, JT=8 ----
constexpr int JT = 8;
__global__ __launch_bounds__(256, 4) void cp_recon_d(const float* __restrict__ W0,
                                                     const float* __restrict__ W1,
                                                     const float* __restrict__ W2,
                                                     float* __restrict__ out) {
    __shared__ __align__(16) float c[JT][RNK];
    const int i     = blockIdx.x >> 5;
    const int jbase = (blockIdx.x & 31) * JT;
    const int tid   = threadIdx.x;

    if (tid < JT * RNK) {
        int jj = tid >> 5;
        int r  = tid & 31;
        c[jj][r] = W0[i * RNK + r] * W1[(jbase + jj) * RNK + r];
    }
    __syncthreads();

    const int k = tid * 4;
    float4 acc[JT];
#pragma unroll
    for (int jj = 0; jj < JT; ++jj) acc[jj] = make_float4(0.f, 0.f, 0.f, 0.f);

    for (int rc = 0; rc < RNK; rc += 4) {
        float4 row[4];
#pragma unroll
        for (int q = 0; q < 4; ++q)
            row[q] = *reinterpret_cast<const float4*>(&W2[(k + q) * RNK + rc]);
#pragma unroll
        for (int jj = 0; jj < JT; ++jj) {
            float4 c4 = *reinterpret_cast<const float4*>(&c[jj][rc]);
            acc[jj].x = fmaf(c4.x, row[0].x, fmaf(c4.y, row[0].y, fmaf(c4.z, row[0].z, fmaf(c4.w, row[0].w, acc[jj].x))));
            acc[jj].y = fmaf(c4.x, row[1].x, fmaf(c4.y, row[1].y, fmaf(c4.z, row[1].z, fmaf(c4.w, row[1].w, acc[jj].y))));
            acc[jj].z = fmaf(c4.x, row[2].x, fmaf(c4.y, row[2].y, fmaf(c4.z, row[2].z, fmaf(c4.w, row[2].w, acc[jj].z))));
            acc[jj].w = fmaf(c4.x, row[3].x, fmaf(c4.y, row[3].y, fmaf(c4.z, row[3].z, fmaf(c4.w, row[3].w, acc[jj].w))));
        }
    }
#pragma unroll
    for (int jj = 0; jj < JT; ++jj) {
        int o = (i * J_DIM + jbase + jj) * K_DIM + k;
        *reinterpret_cast<float4*>(&out[o]) = acc[jj];
    }
}

extern "C" void kernel_launch(void* const* d_in, const int* in_sizes, int n_in,
                              void* d_out, int out_size, void* d_ws, size_t ws_size,
                              hipStream_t stream) {
    const float* W0 = (const float*)d_in[0];
    const float* W1 = (const float*)d_in[1];
    const float* W2 = (const float*)d_in[2];
    float* out = (float*)d_out;

    const size_t w2t_bytes = (size_t)RNK * K_DIM * sizeof(float);          // 128 KB
    const size_t c_bytes   = (size_t)I_DIM * J_DIM * RNK * sizeof(float);  // 8 MB

    if (ws_size >= w2t_bytes + c_bytes) {
        float* W2T  = (float*)d_ws;
        float* Cbuf = (float*)((char*)d_ws + w2t_bytes);
        transpose_w2<<<(RNK * K_DIM) / 256, 256, 0, stream>>>(W2, W2T);
        precompute_c<<<(I_DIM * J_DIM * RNK) / 256, 256, 0, stream>>>(W0, W1, Cbuf);
        const int grid = I_DIM * (J_DIM / JSEG) * KSPLIT;  // 2048
        cp_recon_f2<<<grid, 256, 0, stream>>>(Cbuf, W2T, out);
    } else {
        cp_recon_d<<<I_DIM * (J_DIM / JT), 256, 0, stream>>>(W0, W1, W2, out);
    }
}

// Round 8
// 73.035 us; speedup vs baseline: 2.7839x; 1.0740x over previous
//
#include <hip/hip_runtime.h>

// CP-rank-32: out[i,j,k] = sum_r W0[i,r]*W1[j,r]*W2[k,r]; out 256x256x1024 fp32 (268MB).
// Store-path evidence: NT stores cap ~3.4-3.5 TB/s across R3/R4/R7 (structure-independent,
// occupancy-independent). Plain stores hit 6.9 TB/s in fill kernel but were only tested
// in our kernels at 2 waves/SIMD with long dependent read chains (R5/R6 - serialized).
// R8: R7's kernel (w[32] float2 = 64 VGPR, ~6 waves/SIMD, SMEM c loads) with PLAIN
// stores. Single-variable A/B vs R7 (78us). Expect 48-60us, or declare NT wall roofline.
// FMA order r=0..31 sequential per element — bit-exact across all rounds (absmax 0.0).

constexpr int I_DIM  = 256;
constexpr int J_DIM  = 256;
constexpr int K_DIM  = 1024;
constexpr int RNK    = 32;
constexpr int JSEG   = 64;             // j's per block
constexpr int KSPLIT = 2;              // k-halves
constexpr int KCHUNK = K_DIM / KSPLIT; // 512 k's per block (256 thr * float2)

typedef float f32x2 __attribute__((ext_vector_type(2)));

// W2 (1024x32) -> W2T (32x1024): w loads coalesced in k.
__global__ void transpose_w2(const float* __restrict__ W2, float* __restrict__ W2T) {
    int idx = blockIdx.x * 256 + threadIdx.x;   // 0 .. 32767
    int r = idx >> 10;
    int k = idx & (K_DIM - 1);
    W2T[r * K_DIM + k] = W2[k * RNK + r];
}

// C[i][j][r] = W0[i,r] * W1[j,r]   (8 MB)
__global__ void precompute_c(const float* __restrict__ W0, const float* __restrict__ W1,
                             float* __restrict__ C) {
    int idx = blockIdx.x * 256 + threadIdx.x;
    int r = idx & 31;
    int j = (idx >> 5) & 255;
    int i = idx >> 13;
    C[idx] = W0[i * RNK + r] * W1[j * RNK + r];
}

// Block: (i, jseg, khalf). Thread: one k-float2. w[32] float2 in regs, c via SMEM.
__global__ __launch_bounds__(256, 4) void cp_recon_f2(const float* __restrict__ C,
                                                      const float* __restrict__ W2T,
                                                      float* __restrict__ out) {
    const int b     = blockIdx.x;
    const int khalf = b & (KSPLIT - 1);
    const int jseg  = (b >> 1) & 3;             // J_DIM/JSEG = 4
    const int i     = b >> 3;
    const int jbase = jseg * JSEG;
    const int k     = khalf * KCHUNK + threadIdx.x * 2;

    // Rank-32 W2T slice for this thread's 2 k's: 32 float2 = 64 VGPRs, loaded once.
    float2 w[RNK];
#pragma unroll
    for (int r = 0; r < RNK; ++r)
        w[r] = *reinterpret_cast<const float2*>(&W2T[r * K_DIM + k]);

    const float* __restrict__ crow = C + (size_t)(i * J_DIM + jbase) * RNK;
    float* __restrict__ obase = out + (size_t)(i * J_DIM + jbase) * K_DIM + k;

#pragma unroll 2
    for (int jj = 0; jj < JSEG; ++jj) {
        const float* __restrict__ cj = crow + jj * RNK;  // wave-uniform -> s_load
        float ax = 0.f, ay = 0.f;
#pragma unroll
        for (int r = 0; r < RNK; ++r) {
            float s = cj[r];
            ax = fmaf(s, w[r].x, ax);
            ay = fmaf(s, w[r].y, ay);
        }
        f32x2 t = { ax, ay };
        *reinterpret_cast<f32x2*>(obase + (size_t)jj * K_DIM) = t;  // PLAIN store (A/B vs R7)
    }
}

// ---- Fallback (no ws): direct W2 reads, LDS-c, JT=8 ----
constexpr int JT = 8;
__global__ __launch_bounds__(256, 4) void cp_recon_d(const float* __restrict__ W0,
                                                     const float* __restrict__ W1,
                                                     const float* __restrict__ W2,
                                                     float* __restrict__ out) {
    __shared__ __align__(16) float c[JT][RNK];
    const int i     = blockIdx.x >> 5;
    const int jbase = (blockIdx.x & 31) * JT;
    const int tid   = threadIdx.x;

    if (tid < JT * RNK) {
        int jj = tid >> 5;
        int r  = tid & 31;
        c[jj][r] = W0[i * RNK + r] * W1[(jbase + jj) * RNK + r];
    }
    __syncthreads();

    const int k = tid * 4;
    float4 acc[JT];
#pragma unroll
    for (int jj = 0; jj < JT; ++jj) acc[jj] = make_float4(0.f, 0.f, 0.f, 0.f);

    for (int rc = 0; rc < RNK; rc += 4) {
        float4 row[4];
#pragma unroll
        for (int q = 0; q < 4; ++q)
            row[q] = *reinterpret_cast<const float4*>(&W2[(k + q) * RNK + rc]);
#pragma unroll
        for (int jj = 0; jj < JT; ++jj) {
            float4 c4 = *reinterpret_cast<const float4*>(&c[jj][rc]);
            acc[jj].x = fmaf(c4.x, row[0].x, fmaf(c4.y, row[0].y, fmaf(c4.z, row[0].z, fmaf(c4.w, row[0].w, acc[jj].x))));
            acc[jj].y = fmaf(c4.x, row[1].x, fmaf(c4.y, row[1].y, fmaf(c4.z, row[1].z, fmaf(c4.w, row[1].w, acc[jj].y))));
            acc[jj].z = fmaf(c4.x, row[2].x, fmaf(c4.y, row[2].y, fmaf(c4.z, row[2].z, fmaf(c4.w, row[2].w, acc[jj].z))));
            acc[jj].w = fmaf(c4.x, row[3].x, fmaf(c4.y, row[3].y, fmaf(c4.z, row[3].z, fmaf(c4.w, row[3].w, acc[jj].w))));
        }
    }
#pragma unroll
    for (int jj = 0; jj < JT; ++jj) {
        int o = (i * J_DIM + jbase + jj) * K_DIM + k;
        *reinterpret_cast<float4*>(&out[o]) = acc[jj];
    }
}

extern "C" void kernel_launch(void* const* d_in, const int* in_sizes, int n_in,
                              void* d_out, int out_size, void* d_ws, size_t ws_size,
                              hipStream_t stream) {
    const float* W0 = (const float*)d_in[0];
    const float* W1 = (const float*)d_in[1];
    const float* W2 = (const float*)d_in[2];
    float* out = (float*)d_out;

    const size_t w2t_bytes = (size_t)RNK * K_DIM * sizeof(float);          // 128 KB
    const size_t c_bytes   = (size_t)I_DIM * J_DIM * RNK * sizeof(float);  // 8 MB

    if (ws_size >= w2t_bytes + c_bytes) {
        float* W2T  = (float*)d_ws;
        float* Cbuf = (float*)((char*)d_ws + w2t_bytes);
        transpose_w2<<<(RNK * K_DIM) / 256, 256, 0, stream>>>(W2, W2T);
        precompute_c<<<(I_DIM * J_DIM * RNK) / 256, 256, 0, stream>>>(W0, W1, Cbuf);
        const int grid = I_DIM * (J_DIM / JSEG) * KSPLIT;  // 2048
        cp_recon_f2<<<grid, 256, 0, stream>>>(Cbuf, W2T, out);
    } else {
        cp_recon_d<<<I_DIM * (J_DIM / JT), 256, 0, stream>>>(W0, W1, W2, out);
    }
}